// Round 2
// baseline (870.958 us; speedup 1.0000x reference)
//
#include <hip/hip_runtime.h>
#include <math.h>

// Routing-by-agreement v4: 5-launch fused chain (no cooperative launch).
//
// Algebra: logits at iter k = b + u.(v0+...+v_{k-1}) = b + u.w  (linear), so
// each pass needs ONE dot against the running sum w.
//
// v4 structure (kernel boundary = free grid barrier, replaces v3's grid.sync):
//   pass0_convert : inline softmax(b), s0-partials, fp16 copy of u   [2048 blk]
//   pass_iter<1>  : prologue v0=squash(part0) -> w=v0 (chunk0 writes wA),
//                   stream u16, partials -> part1                     [2048 blk]
//   pass_iter<2>  : v1=squash(part1), w=wA+v1 (writes wB), -> part0   [2048 blk]
//   pass_iter<3>  : v2=squash(part0), w=wB+v2,            -> part1   [2048 blk]
//   reduce_out    : v3=squash(part1) -> out                          [256 blk]
//
// The reduce prologue is redundant per block (16x512 floats = 32 KB, L2-hot);
// replaces 3 dedicated reduce kernels + softmax kernel + global w round trips.
// Streaming loops are byte-identical to the verified 856us v2.1 kernels.
//
// Traffic: 537 MB fp32 read + 268 MB fp16 write (pass0); 3 x 268 MB fp16 read.
// Roofline ~280 us.

namespace {
constexpr int BATCH = 128;
constexpr int IC    = 2048;
constexpr int OC    = 32;
constexpr int ROW   = 512;                    // OC*OD floats per (b,i) row
constexpr int BPB   = 16;                     // blocks (chunks) per batch
constexpr int ROWS_PER_BLOCK = IC / BPB;      // 128
constexpr int NWAVES = 4;                     // 256 threads
constexpr int HROW  = ROW / 8;                // row stride in half8 units = 64

typedef _Float16 half8 __attribute__((ext_vector_type(8)));
typedef float    f32x4 __attribute__((ext_vector_type(4)));

// workspace carve (bytes)
constexpr size_t OFF_U16    = 0;                                // 256 MiB
constexpr size_t PART_BYTES = (size_t)BATCH * BPB * ROW * 4;    // 4 MiB
constexpr size_t OFF_P0     = 268435456;
constexpr size_t OFF_P1     = OFF_P0 + PART_BYTES;
constexpr size_t OFF_WA     = OFF_P1 + PART_BYTES;              // 256 KiB
constexpr size_t OFF_WB     = OFF_WA + 262144;                  // 256 KiB
} // namespace

// ---------------------------------------------------------------------------
// pass 0: s0_partial = sum_i softmax(b)[i,o]*u  AND write fp16 copy of u.
__global__ void __launch_bounds__(256)
pass0_convert(const float* __restrict__ u, const float* __restrict__ blogit,
              _Float16* __restrict__ u16, float* __restrict__ partials)
{
    const int tid = threadIdx.x, lane = tid & 63, wave = tid >> 6;
    const int b = blockIdx.x >> 4, chunk = blockIdx.x & 15;
    const int o = lane >> 1, elem0 = lane * 8;
    const int i_base = chunk * ROWS_PER_BLOCK + wave * 32;

    f32x4 acc0 = {0.f,0.f,0.f,0.f}, acc1 = {0.f,0.f,0.f,0.f};

    const float*  ubase = u   + ((size_t)b * IC + i_base) * ROW + elem0;
    _Float16*     obase = u16 + ((size_t)b * IC + i_base) * ROW + elem0;

#pragma unroll 4
    for (int r = 0; r < 32; ++r) {
        const float* up = ubase + (size_t)r * ROW;
        f32x4 u0 = __builtin_nontemporal_load((const f32x4*)up);
        f32x4 u1 = __builtin_nontemporal_load((const f32x4*)(up + 4));
        // inline softmax of blogit row over the 32 o (no max-sub; b==0 here ->
        // e=1, ssum=32 -- identical result to the old dedicated softmax kernel)
        float e = __expf(blogit[(i_base + r) * OC + o]);
        float ssum = e;
#pragma unroll
        for (int off = 2; off <= 32; off <<= 1)
            ssum += __shfl_xor(ssum, off, 64);
        const float c = e / ssum;
        acc0 += c * u0;
        acc1 += c * u1;
        half8 h;
        h[0]=(_Float16)u0[0]; h[1]=(_Float16)u0[1]; h[2]=(_Float16)u0[2]; h[3]=(_Float16)u0[3];
        h[4]=(_Float16)u1[0]; h[5]=(_Float16)u1[1]; h[6]=(_Float16)u1[2]; h[7]=(_Float16)u1[3];
        __builtin_nontemporal_store(h, (half8*)(obase + (size_t)r * ROW));
    }

    __shared__ float red[NWAVES * ROW];   // 8 KiB
    float* my = red + wave * ROW + elem0;
    *(f32x4*)my       = acc0;
    *(f32x4*)(my + 4) = acc1;
    __syncthreads();
    float* dst = partials + (size_t)blockIdx.x * ROW;
    for (int p = tid; p < ROW; p += 256)
        dst[p] = red[p] + red[ROW + p] + red[2*ROW + p] + red[3*ROW + p];
}

// ---------------------------------------------------------------------------
// prologue: v = squash(sum of 16 chunk partials); w = (IT==1 ? v : w_in + v).
// Every block computes its batch's w redundantly; chunk==0 persists it.
template<int IT>
__device__ __forceinline__ void compute_w(const float* __restrict__ part_in,
                                          const float* __restrict__ w_in,
                                          float* __restrict__ w_out,
                                          float* __restrict__ wlds,
                                          int b, int tid, int chunk)
{
    const int p = tid * 2;
    const float* pp = part_in + (size_t)b * (BPB * ROW) + p;
    float s0 = 0.f, s1 = 0.f;
#pragma unroll
    for (int k = 0; k < BPB; ++k) {
        s0 += pp[(size_t)k * ROW];
        s1 += pp[(size_t)k * ROW + 1];
    }
    float sq = s0 * s0 + s1 * s1;          // thread holds 2 of the 16 d of one o
    sq += __shfl_xor(sq, 1, 64);
    sq += __shfl_xor(sq, 2, 64);
    sq += __shfl_xor(sq, 4, 64);           // 8-lane group = one o
    const float sc = sqrtf(sq) / (1.0f + sq);
    float w0 = s0 * sc, w1 = s1 * sc;
    if (IT > 1) {
        w0 += w_in[b * ROW + p];
        w1 += w_in[b * ROW + p + 1];
    }
    wlds[p]     = w0;
    wlds[p + 1] = w1;
    if (IT < 3 && chunk == 0) {
        w_out[b * ROW + p]     = w0;
        w_out[b * ROW + p + 1] = w1;
    }
}

// one routing iteration: logits = b + u.w, softmax over o, s_partial = sum c*u
template<int IT>
__global__ void __launch_bounds__(256)
pass_iter(const _Float16* __restrict__ u16, const float* __restrict__ blogit,
          const float* __restrict__ part_in, const float* __restrict__ w_in,
          float* __restrict__ part_out, float* __restrict__ w_out)
{
    const int tid = threadIdx.x, lane = tid & 63, wave = tid >> 6;
    const int b = blockIdx.x >> 4, chunk = blockIdx.x & 15;
    const int o = lane >> 1, elem0 = lane * 8;
    const int i_base = chunk * ROWS_PER_BLOCK + wave * 32;

    __shared__ float red[NWAVES * ROW];   // 8 KiB
    __shared__ float wlds[ROW];           // 2 KiB

    const half8* ubase = (const half8*)(u16 + ((size_t)b * IC + i_base) * ROW + elem0);

    // issue first row-group loads BEFORE the prologue so HBM latency hides it
    half8 cur[4];
    cur[0] = ubase[0*HROW]; cur[1] = ubase[1*HROW];
    cur[2] = ubase[2*HROW]; cur[3] = ubase[3*HROW];

    compute_w<IT>(part_in, w_in, w_out, wlds, b, tid, chunk);
    __syncthreads();

    const f32x4 w0 = *(const f32x4*)(wlds + elem0);
    const f32x4 w1 = *(const f32x4*)(wlds + elem0 + 4);

    f32x4 acc0 = {0.f,0.f,0.f,0.f}, acc1 = {0.f,0.f,0.f,0.f};

    for (int g = 0; g < 8; ++g) {
        half8 nxt[4];
        if (g < 7) {
            const half8* ptr = ubase + (size_t)(g + 1) * 4 * HROW;
            nxt[0] = ptr[0*HROW]; nxt[1] = ptr[1*HROW];
            nxt[2] = ptr[2*HROW]; nxt[3] = ptr[3*HROW];
        }
        float blg[4];
#pragma unroll
        for (int r = 0; r < 4; ++r)
            blg[r] = blogit[(i_base + g*4 + r) * OC + o];

#pragma unroll
        for (int r = 0; r < 4; ++r) {
            float uf[8];
#pragma unroll
            for (int j = 0; j < 8; ++j) uf[j] = (float)cur[r][j];
            float part = uf[0]*w0[0] + uf[1]*w0[1] + uf[2]*w0[2] + uf[3]*w0[3]
                       + uf[4]*w1[0] + uf[5]*w1[1] + uf[6]*w1[2] + uf[7]*w1[3];
            float bb = blg[r] + part + __shfl_xor(part, 1, 64);
            // softmax over the 32 distinct o, no max-subtraction (|bb| <~ 30)
            float e = __expf(bb);
            float ssum = e;
#pragma unroll
            for (int off = 2; off <= 32; off <<= 1)
                ssum += __shfl_xor(ssum, off, 64);
            const float c = e / ssum;
            acc0[0] += c*uf[0]; acc0[1] += c*uf[1]; acc0[2] += c*uf[2]; acc0[3] += c*uf[3];
            acc1[0] += c*uf[4]; acc1[1] += c*uf[5]; acc1[2] += c*uf[6]; acc1[3] += c*uf[7];
        }
#pragma unroll
        for (int r = 0; r < 4; ++r) cur[r] = nxt[r];
    }

    float* my = red + wave * ROW + elem0;
    *(f32x4*)my       = acc0;
    *(f32x4*)(my + 4) = acc1;
    __syncthreads();
    float* dst = part_out + (size_t)blockIdx.x * ROW;
    for (int p = tid; p < ROW; p += 256)
        dst[p] = red[p] + red[ROW + p] + red[2*ROW + p] + red[3*ROW + p];
}

// ---------------------------------------------------------------------------
// final: sum 16 partials per (b,p), squash, write output.
__global__ void __launch_bounds__(256)
reduce_out(const float* __restrict__ partials, float* __restrict__ out)
{
    const int idx = blockIdx.x * 256 + threadIdx.x;  // over BATCH*ROW = 65536
    const int b = idx >> 9, p = idx & 511;
    const float* pp = partials + (size_t)(b * BPB) * ROW + p;
    float s = 0.f;
#pragma unroll
    for (int k = 0; k < BPB; ++k) s += pp[(size_t)k * ROW];
    float sq = s * s;
    sq += __shfl_xor(sq, 1, 64);
    sq += __shfl_xor(sq, 2, 64);
    sq += __shfl_xor(sq, 4, 64);
    sq += __shfl_xor(sq, 8, 64);           // 16 lanes = the 16 d of one o
    out[idx] = s * (sqrtf(sq) / (1.0f + sq));
}

// ---------------------------------------------------------------------------
extern "C" void kernel_launch(void* const* d_in, const int* in_sizes, int n_in,
                              void* d_out, int out_size, void* d_ws, size_t ws_size,
                              hipStream_t stream)
{
    const float* u  = (const float*)d_in[0];   // [128,2048,32,16] fp32
    const float* bl = (const float*)d_in[1];   // [2048,32] fp32
    float* out = (float*)d_out;                // [128,32,16] fp32

    char* ws = (char*)d_ws;
    _Float16* u16 = (_Float16*)(ws + OFF_U16);
    float* part0  = (float*)(ws + OFF_P0);
    float* part1  = (float*)(ws + OFF_P1);
    float* wA     = (float*)(ws + OFF_WA);
    float* wB     = (float*)(ws + OFF_WB);

    const dim3 blk(256);
    const dim3 gpass(BATCH * BPB);             // 2048

    pass0_convert<<<gpass, blk, 0, stream>>>(u, bl, u16, part0);
    pass_iter<1> <<<gpass, blk, 0, stream>>>(u16, bl, part0, nullptr, part1, wA);
    pass_iter<2> <<<gpass, blk, 0, stream>>>(u16, bl, part1, wA,      part0, wB);
    pass_iter<3> <<<gpass, blk, 0, stream>>>(u16, bl, part0, wB,      part1, nullptr);
    reduce_out   <<<dim3(BATCH * ROW / 256), blk, 0, stream>>>(part1, out);
}

// Round 3
// 855.535 us; speedup vs baseline: 1.0180x; 1.0180x over previous
//
#include <hip/hip_runtime.h>
#include <math.h>

// Routing-by-agreement v5: batch-halved fused chain for L3 (Infinity Cache)
// residency of the fp16 copy of u.
//
// Algebra: logits at iter k = b + u.(v0+...+v_{k-1}) = b + u.w  (linear), so
// each pass needs ONE dot against the running sum w (maintained via partials).
//
// v5 vs v4:
//  - chain runs per batch-HALF (64 batches): u16 half = 128 MiB, stays resident
//    in the 256 MiB Infinity Cache from pass0's write through iter3's read, so
//    the three re-read sweeps run at L3 bandwidth instead of HBM.
//  - u16 stores are PLAIN (cached) -- v4's nontemporal store told the cache
//    hierarchy to drop exactly the lines we re-read 3x. fp32 u reads stay
//    nontemporal so the 268 MB stream does not evict u16.
//
// Per half: pass0 reads 268 MB fp32 (nt) + writes 128 MiB fp16 (cached),
// iters read 128 MiB fp16 (L3-hot) each. Chain roofline ~90 us/half at HBM,
// less with L3 hits on the iter sweeps.

namespace {
constexpr int BATCH = 128;
constexpr int BHALF = 64;                     // batches per half-chain
constexpr int IC    = 2048;
constexpr int OC    = 32;
constexpr int ROW   = 512;                    // OC*OD floats per (b,i) row
constexpr int BPB   = 16;                     // blocks (chunks) per batch
constexpr int ROWS_PER_BLOCK = IC / BPB;      // 128
constexpr int NWAVES = 4;                     // 256 threads
constexpr int HROW  = ROW / 8;                // row stride in half8 units = 64

typedef _Float16 half8 __attribute__((ext_vector_type(8)));
typedef float    f32x4 __attribute__((ext_vector_type(4)));

// workspace carve (bytes)
constexpr size_t OFF_U16    = 0;                                // 256 MiB
constexpr size_t PART_BYTES = (size_t)BATCH * BPB * ROW * 4;    // 4 MiB
constexpr size_t OFF_P0     = 268435456;
constexpr size_t OFF_P1     = OFF_P0 + PART_BYTES;
constexpr size_t OFF_WA     = OFF_P1 + PART_BYTES;              // 256 KiB
constexpr size_t OFF_WB     = OFF_WA + 262144;                  // 256 KiB
} // namespace

// ---------------------------------------------------------------------------
// pass 0: s0_partial = sum_i softmax(b)[i,o]*u  AND write fp16 copy of u.
__global__ void __launch_bounds__(256)
pass0_convert(const float* __restrict__ u, const float* __restrict__ blogit,
              _Float16* __restrict__ u16, float* __restrict__ partials, int b0)
{
    const int tid = threadIdx.x, lane = tid & 63, wave = tid >> 6;
    const int b = b0 + (blockIdx.x >> 4), chunk = blockIdx.x & 15;
    const int o = lane >> 1, elem0 = lane * 8;
    const int i_base = chunk * ROWS_PER_BLOCK + wave * 32;

    f32x4 acc0 = {0.f,0.f,0.f,0.f}, acc1 = {0.f,0.f,0.f,0.f};

    const float*  ubase = u   + ((size_t)b * IC + i_base) * ROW + elem0;
    _Float16*     obase = u16 + ((size_t)b * IC + i_base) * ROW + elem0;

#pragma unroll 4
    for (int r = 0; r < 32; ++r) {
        const float* up = ubase + (size_t)r * ROW;
        f32x4 u0 = __builtin_nontemporal_load((const f32x4*)up);
        f32x4 u1 = __builtin_nontemporal_load((const f32x4*)(up + 4));
        // inline softmax of blogit row over the 32 o (no max-sub; b==0 here ->
        // e=1, ssum=32 -- identical result to a dedicated softmax kernel)
        float e = __expf(blogit[(i_base + r) * OC + o]);
        float ssum = e;
#pragma unroll
        for (int off = 2; off <= 32; off <<= 1)
            ssum += __shfl_xor(ssum, off, 64);
        const float c = e / ssum;
        acc0 += c * u0;
        acc1 += c * u1;
        half8 h;
        h[0]=(_Float16)u0[0]; h[1]=(_Float16)u0[1]; h[2]=(_Float16)u0[2]; h[3]=(_Float16)u0[3];
        h[4]=(_Float16)u1[0]; h[5]=(_Float16)u1[1]; h[6]=(_Float16)u1[2]; h[7]=(_Float16)u1[3];
        *(half8*)(obase + (size_t)r * ROW) = h;   // cached store: keep in L3
    }

    __shared__ float red[NWAVES * ROW];   // 8 KiB
    float* my = red + wave * ROW + elem0;
    *(f32x4*)my       = acc0;
    *(f32x4*)(my + 4) = acc1;
    __syncthreads();
    float* dst = partials + ((size_t)b * BPB + chunk) * ROW;
    for (int p = tid; p < ROW; p += 256)
        dst[p] = red[p] + red[ROW + p] + red[2*ROW + p] + red[3*ROW + p];
}

// ---------------------------------------------------------------------------
// prologue: v = squash(sum of 16 chunk partials); w = (IT==1 ? v : w_in + v).
// Every block computes its batch's w redundantly; chunk==0 persists it.
template<int IT>
__device__ __forceinline__ void compute_w(const float* __restrict__ part_in,
                                          const float* __restrict__ w_in,
                                          float* __restrict__ w_out,
                                          float* __restrict__ wlds,
                                          int b, int tid, int chunk)
{
    const int p = tid * 2;
    const float* pp = part_in + (size_t)b * (BPB * ROW) + p;
    float s0 = 0.f, s1 = 0.f;
#pragma unroll
    for (int k = 0; k < BPB; ++k) {
        s0 += pp[(size_t)k * ROW];
        s1 += pp[(size_t)k * ROW + 1];
    }
    float sq = s0 * s0 + s1 * s1;          // thread holds 2 of the 16 d of one o
    sq += __shfl_xor(sq, 1, 64);
    sq += __shfl_xor(sq, 2, 64);
    sq += __shfl_xor(sq, 4, 64);           // 8-lane group = one o
    const float sc = sqrtf(sq) / (1.0f + sq);
    float w0 = s0 * sc, w1 = s1 * sc;
    if (IT > 1) {
        w0 += w_in[b * ROW + p];
        w1 += w_in[b * ROW + p + 1];
    }
    wlds[p]     = w0;
    wlds[p + 1] = w1;
    if (IT < 3 && chunk == 0) {
        w_out[b * ROW + p]     = w0;
        w_out[b * ROW + p + 1] = w1;
    }
}

// one routing iteration: logits = b + u.w, softmax over o, s_partial = sum c*u
template<int IT>
__global__ void __launch_bounds__(256)
pass_iter(const _Float16* __restrict__ u16, const float* __restrict__ blogit,
          const float* __restrict__ part_in, const float* __restrict__ w_in,
          float* __restrict__ part_out, float* __restrict__ w_out, int b0)
{
    const int tid = threadIdx.x, lane = tid & 63, wave = tid >> 6;
    const int b = b0 + (blockIdx.x >> 4), chunk = blockIdx.x & 15;
    const int o = lane >> 1, elem0 = lane * 8;
    const int i_base = chunk * ROWS_PER_BLOCK + wave * 32;

    __shared__ float red[NWAVES * ROW];   // 8 KiB
    __shared__ float wlds[ROW];           // 2 KiB

    const half8* ubase = (const half8*)(u16 + ((size_t)b * IC + i_base) * ROW + elem0);

    // issue first row-group loads BEFORE the prologue so load latency hides
    half8 cur[4];
    cur[0] = ubase[0*HROW]; cur[1] = ubase[1*HROW];
    cur[2] = ubase[2*HROW]; cur[3] = ubase[3*HROW];

    compute_w<IT>(part_in, w_in, w_out, wlds, b, tid, chunk);
    __syncthreads();

    const f32x4 w0 = *(const f32x4*)(wlds + elem0);
    const f32x4 w1 = *(const f32x4*)(wlds + elem0 + 4);

    f32x4 acc0 = {0.f,0.f,0.f,0.f}, acc1 = {0.f,0.f,0.f,0.f};

    for (int g = 0; g < 8; ++g) {
        half8 nxt[4];
        if (g < 7) {
            const half8* ptr = ubase + (size_t)(g + 1) * 4 * HROW;
            nxt[0] = ptr[0*HROW]; nxt[1] = ptr[1*HROW];
            nxt[2] = ptr[2*HROW]; nxt[3] = ptr[3*HROW];
        }
        float blg[4];
#pragma unroll
        for (int r = 0; r < 4; ++r)
            blg[r] = blogit[(i_base + g*4 + r) * OC + o];

#pragma unroll
        for (int r = 0; r < 4; ++r) {
            float uf[8];
#pragma unroll
            for (int j = 0; j < 8; ++j) uf[j] = (float)cur[r][j];
            float part = uf[0]*w0[0] + uf[1]*w0[1] + uf[2]*w0[2] + uf[3]*w0[3]
                       + uf[4]*w1[0] + uf[5]*w1[1] + uf[6]*w1[2] + uf[7]*w1[3];
            float bb = blg[r] + part + __shfl_xor(part, 1, 64);
            // softmax over the 32 distinct o, no max-subtraction (|bb| <~ 30)
            float e = __expf(bb);
            float ssum = e;
#pragma unroll
            for (int off = 2; off <= 32; off <<= 1)
                ssum += __shfl_xor(ssum, off, 64);
            const float c = e / ssum;
            acc0[0] += c*uf[0]; acc0[1] += c*uf[1]; acc0[2] += c*uf[2]; acc0[3] += c*uf[3];
            acc1[0] += c*uf[4]; acc1[1] += c*uf[5]; acc1[2] += c*uf[6]; acc1[3] += c*uf[7];
        }
#pragma unroll
        for (int r = 0; r < 4; ++r) cur[r] = nxt[r];
    }

    float* my = red + wave * ROW + elem0;
    *(f32x4*)my       = acc0;
    *(f32x4*)(my + 4) = acc1;
    __syncthreads();
    float* dst = part_out + ((size_t)b * BPB + chunk) * ROW;
    for (int p = tid; p < ROW; p += 256)
        dst[p] = red[p] + red[ROW + p] + red[2*ROW + p] + red[3*ROW + p];
}

// ---------------------------------------------------------------------------
// final: sum 16 partials per (b,p), squash, write output.
__global__ void __launch_bounds__(256)
reduce_out(const float* __restrict__ partials, float* __restrict__ out, int b0)
{
    const int idx = b0 * ROW + blockIdx.x * 256 + threadIdx.x;
    const int b = idx >> 9, p = idx & 511;
    const float* pp = partials + (size_t)(b * BPB) * ROW + p;
    float s = 0.f;
#pragma unroll
    for (int k = 0; k < BPB; ++k) s += pp[(size_t)k * ROW];
    float sq = s * s;
    sq += __shfl_xor(sq, 1, 64);
    sq += __shfl_xor(sq, 2, 64);
    sq += __shfl_xor(sq, 4, 64);
    sq += __shfl_xor(sq, 8, 64);           // 16 lanes = the 16 d of one o
    out[idx] = s * (sqrtf(sq) / (1.0f + sq));
}

// ---------------------------------------------------------------------------
extern "C" void kernel_launch(void* const* d_in, const int* in_sizes, int n_in,
                              void* d_out, int out_size, void* d_ws, size_t ws_size,
                              hipStream_t stream)
{
    const float* u  = (const float*)d_in[0];   // [128,2048,32,16] fp32
    const float* bl = (const float*)d_in[1];   // [2048,32] fp32
    float* out = (float*)d_out;                // [128,32,16] fp32

    char* ws = (char*)d_ws;
    _Float16* u16 = (_Float16*)(ws + OFF_U16);
    float* part0  = (float*)(ws + OFF_P0);
    float* part1  = (float*)(ws + OFF_P1);
    float* wA     = (float*)(ws + OFF_WA);
    float* wB     = (float*)(ws + OFF_WB);

    const dim3 blk(256);
    const dim3 gpass(BHALF * BPB);             // 1024 blocks per half-chain
    const dim3 gred(BHALF * ROW / 256);        // 128

    for (int h = 0; h < 2; ++h) {
        const int b0 = h * BHALF;
        pass0_convert<<<gpass, blk, 0, stream>>>(u, bl, u16, part0, b0);
        pass_iter<1> <<<gpass, blk, 0, stream>>>(u16, bl, part0, nullptr, part1, wA, b0);
        pass_iter<2> <<<gpass, blk, 0, stream>>>(u16, bl, part1, wA,      part0, wB, b0);
        pass_iter<3> <<<gpass, blk, 0, stream>>>(u16, bl, part0, wB,      part1, nullptr, b0);
        reduce_out   <<<gred,  blk, 0, stream>>>(part1, out, b0);
    }
}